// Round 1
// baseline (484.200 us; speedup 1.0000x reference)
//
#include <hip/hip_runtime.h>

// HeavySnow: stamp flakes (0.95 squares, all channels) -> depthwise 5x5
// gaussian blur (zero pad) -> clip [0,1].
// R3: vertical-first blur. v-pass reads directly from global (5x re-read is
// L1/L2-resident: block working set 19.6 KB), flake substitution inline from
// direct mask-word loads. One LDS array (17.9 KB -> 8 blocks/CU = 32 waves/CU),
// one __syncthreads (was 3). h-pass + clip + float4 store.

#define H_ 1024
#define W_ 1024
#define B_ 16
#define C_ 3
#define NF_ 15728
#define MASK_WORDS_PER_B (H_ * W_ / 32)  // 32768 words (128 KB) per batch

// Gaussian weights: sigma=1.5, K=5, normalized. g = [g0,g1,g2,g1,g0].
#define G0 0.12007838f
#define G1 0.23388076f
#define G2 0.29208172f

__global__ void clear_mask_kernel(uint4* __restrict__ mask, int n4) {
    int i = blockIdx.x * blockDim.x + threadIdx.x;
    if (i < n4) mask[i] = make_uint4(0u, 0u, 0u, 0u);
}

__global__ void stamp_kernel(const int* __restrict__ ys, const int* __restrict__ xs,
                             const int* __restrict__ rs, unsigned int* __restrict__ mask) {
    int t = blockIdx.x * blockDim.x + threadIdx.x;
    if (t >= B_ * NF_) return;
    int b = t / NF_;
    int y0 = ys[t], x0 = xs[t], r = rs[t];
    unsigned int* mb = mask + b * MASK_WORDS_PER_B;
    int xlo = max(x0 - r, 0), xhi = min(x0 + r, W_ - 1);
    int ylo = max(y0 - r, 0), yhi = min(y0 + r, H_ - 1);
    for (int y = ylo; y <= yhi; ++y) {
        int i0 = (y << 10) + xlo;
        int i1 = (y << 10) + xhi;
        int w0 = i0 >> 5, w1 = i1 >> 5;
        unsigned int m0 = ~0u << (i0 & 31);
        unsigned int m1 = ~0u >> (31 - (i1 & 31));
        if (w0 == w1) {
            atomicOr(mb + w0, m0 & m1);
        } else {
            atomicOr(mb + w0, m0);
            atomicOr(mb + w1, m1);
        }
    }
}

// Tiled separable 5x5 blur, vertical-first, fused flake substitution and clip.
// Output tile: 128 wide (32 float4) x 32 high.
constexpr int TW = 128;
constexpr int TH = 32;

__global__ __launch_bounds__(256) void blur_kernel(const float* __restrict__ x,
                                                   const unsigned int* __restrict__ mask,
                                                   float* __restrict__ out) {
    int plane = blockIdx.z;            // b*C + c
    int b = plane / C_;
    const float* xp = x + (size_t)plane * (H_ * W_);
    float* op = out + (size_t)plane * (H_ * W_);
    const unsigned int* mb = mask + b * MASK_WORDS_PER_B;

    const int tx0 = blockIdx.x * TW;
    const int ty0 = blockIdx.y * TH;
    const int tid = threadIdx.x;

    // v-filtered tile: rows ty0..ty0+31, scalar cols tx0-4 .. tx0+131
    // (34 float4 used, +1 pad col to keep row stride off a power of two)
    __shared__ float4 smid[TH][35];

    // ---- phase A: vertical pass from global + flake substitution ----
    for (int i = tid; i < TH * 34; i += 256) {
        int r = i / 34;
        int j = i - 34 * r;
        int gx4 = tx0 - 4 + 4 * j;             // 4-aligned scalar col
        float4 acc = make_float4(0.f, 0.f, 0.f, 0.f);
        if ((unsigned)gx4 < (unsigned)W_) {
            int cw = gx4 >> 5;
            int bit = gx4 & 31;
            int gy0 = ty0 + r - 2;
            #pragma unroll
            for (int k = 0; k < 5; ++k) {
                const float wk = (k == 0 || k == 4) ? G0 : ((k == 1 || k == 3) ? G1 : G2);
                int gy = gy0 + k;
                if ((unsigned)gy < (unsigned)H_) {
                    float4 v = *(const float4*)(xp + (gy << 10) + gx4);
                    unsigned int mw = mb[(gy << 5) + cw];
                    if ((mw >> (bit + 0)) & 1u) v.x = 0.95f;
                    if ((mw >> (bit + 1)) & 1u) v.y = 0.95f;
                    if ((mw >> (bit + 2)) & 1u) v.z = 0.95f;
                    if ((mw >> (bit + 3)) & 1u) v.w = 0.95f;
                    acc.x += wk * v.x;
                    acc.y += wk * v.y;
                    acc.z += wk * v.z;
                    acc.w += wk * v.w;
                }
            }
        }
        smid[r][j] = acc;
    }
    __syncthreads();

    // ---- phase B: horizontal pass + clip + float4 store ----
    for (int i = tid; i < TH * 32; i += 256) {
        int rr = i >> 5;
        int j = i & 31;
        // scalar cols needed: s2..s9 relative to 4j in halo space (offset -4)
        float2 A  = *(const float2*)((const float*)&smid[rr][j] + 2);     // s2,s3
        float4 Bv = smid[rr][j + 1];                                       // s4..s7
        float2 Cv = *(const float2*)((const float*)&smid[rr][j + 2]);      // s8,s9
        float4 o;
        o.x = G0 * (A.x  + Bv.z) + G1 * (A.y  + Bv.y) + G2 * Bv.x;
        o.y = G0 * (A.y  + Bv.w) + G1 * (Bv.x + Bv.z) + G2 * Bv.y;
        o.z = G0 * (Bv.x + Cv.x) + G1 * (Bv.y + Bv.w) + G2 * Bv.z;
        o.w = G0 * (Bv.y + Cv.y) + G1 * (Bv.z + Cv.x) + G2 * Bv.w;
        o.x = fminf(fmaxf(o.x, 0.0f), 1.0f);
        o.y = fminf(fmaxf(o.y, 0.0f), 1.0f);
        o.z = fminf(fmaxf(o.z, 0.0f), 1.0f);
        o.w = fminf(fmaxf(o.w, 0.0f), 1.0f);
        *(float4*)(op + ((ty0 + rr) << 10) + tx0 + 4 * j) = o;
    }
}

extern "C" void kernel_launch(void* const* d_in, const int* in_sizes, int n_in,
                              void* d_out, int out_size, void* d_ws, size_t ws_size,
                              hipStream_t stream) {
    const float* x  = (const float*)d_in[0];
    const int*   ys = (const int*)d_in[1];
    const int*   xs = (const int*)d_in[2];
    const int*   rs = (const int*)d_in[3];
    float* out = (float*)d_out;
    unsigned int* mask = (unsigned int*)d_ws;  // 16 * 32768 words = 2 MB

    int n4 = B_ * MASK_WORDS_PER_B / 4;
    clear_mask_kernel<<<dim3((n4 + 255) / 256), dim3(256), 0, stream>>>((uint4*)mask, n4);

    int nst = B_ * NF_;
    stamp_kernel<<<dim3((nst + 255) / 256), dim3(256), 0, stream>>>(ys, xs, rs, mask);

    dim3 grid(W_ / TW, H_ / TH, B_ * C_);
    blur_kernel<<<grid, dim3(256), 0, stream>>>(x, mask, out);
}

// Round 2
// 403.761 us; speedup vs baseline: 1.1992x; 1.1992x over previous
//
#include <hip/hip_runtime.h>

// HeavySnow: stamp flakes (0.95 squares, all channels) -> depthwise 5x5
// gaussian blur (zero pad) -> clip [0,1].
// R4: single-LDS-array blur. Stage raw x tile (36x34 float4) with inline
// flake substitution (mask words read direct from global; L2-resident).
// One __syncthreads. Each thread v-filters 3 halo words in registers
// (15 LDS reads/output float4), then h-filter + clip + float4 store.
// LDS 20.2 KB -> 8 blocks/CU (32 waves/CU), vs R2's 38.9 KB / 4 blocks / 3 syncs.

#define H_ 1024
#define W_ 1024
#define B_ 16
#define C_ 3
#define NF_ 15728
#define MASK_WORDS_PER_B (H_ * W_ / 32)  // 32768 words (128 KB) per batch

// Gaussian weights: sigma=1.5, K=5, normalized. g = [g0,g1,g2,g1,g0].
#define G0 0.12007838f
#define G1 0.23388076f
#define G2 0.29208172f

__global__ void clear_mask_kernel(uint4* __restrict__ mask, int n4) {
    int i = blockIdx.x * blockDim.x + threadIdx.x;
    if (i < n4) mask[i] = make_uint4(0u, 0u, 0u, 0u);
}

__global__ void stamp_kernel(const int* __restrict__ ys, const int* __restrict__ xs,
                             const int* __restrict__ rs, unsigned int* __restrict__ mask) {
    int t = blockIdx.x * blockDim.x + threadIdx.x;
    if (t >= B_ * NF_) return;
    int b = t / NF_;
    int y0 = ys[t], x0 = xs[t], r = rs[t];
    unsigned int* mb = mask + b * MASK_WORDS_PER_B;
    int xlo = max(x0 - r, 0), xhi = min(x0 + r, W_ - 1);
    int ylo = max(y0 - r, 0), yhi = min(y0 + r, H_ - 1);
    for (int y = ylo; y <= yhi; ++y) {
        int i0 = (y << 10) + xlo;
        int i1 = (y << 10) + xhi;
        int w0 = i0 >> 5, w1 = i1 >> 5;
        unsigned int m0 = ~0u << (i0 & 31);
        unsigned int m1 = ~0u >> (31 - (i1 & 31));
        if (w0 == w1) {
            atomicOr(mb + w0, m0 & m1);
        } else {
            atomicOr(mb + w0, m0);
            atomicOr(mb + w1, m1);
        }
    }
}

// Tiled separable 5x5 blur, fused flake substitution and clip.
// Output tile: 128 wide (32 float4) x 32 high. Halo 2 each side.
constexpr int TW = 128;
constexpr int TH = 32;

__global__ __launch_bounds__(256) void blur_kernel(const float* __restrict__ x,
                                                   const unsigned int* __restrict__ mask,
                                                   float* __restrict__ out) {
    int plane = blockIdx.z;            // b*C + c
    int b = plane / C_;
    const float* xp = x + (size_t)plane * (H_ * W_);
    float* op = out + (size_t)plane * (H_ * W_);
    const unsigned int* mb = mask + b * MASK_WORDS_PER_B;

    const int tx0 = blockIdx.x * TW;
    const int ty0 = blockIdx.y * TH;
    const int tid = threadIdx.x;

    // Raw (flake-substituted) input tile: rows ty0-2 .. ty0+33,
    // float4 word w covers scalar cols tx0-4+4w .. tx0-4+4w+3, w = 0..33.
    // 35th col = pad (row stride 140 dwords, != 0 mod 32-bank-friendly).
    __shared__ float4 sin4[TH + 4][35];

    // ---- phase A: stage input + flake substitution (mask read direct) ----
    for (int i = tid; i < (TH + 4) * 34; i += 256) {
        int r = i / 34;
        int j = i - 34 * r;
        int gy = ty0 + r - 2;
        int gx4 = tx0 - 4 + 4 * j;             // 4-aligned scalar col
        float4 v = make_float4(0.f, 0.f, 0.f, 0.f);
        if ((unsigned)gy < (unsigned)H_ && (unsigned)gx4 < (unsigned)W_) {
            v = *(const float4*)(xp + (gy << 10) + gx4);
            unsigned int mw = mb[(gy << 5) + (gx4 >> 5)];
            int bit = gx4 & 31;
            if ((mw >> (bit + 0)) & 1u) v.x = 0.95f;
            if ((mw >> (bit + 1)) & 1u) v.y = 0.95f;
            if ((mw >> (bit + 2)) & 1u) v.z = 0.95f;
            if ((mw >> (bit + 3)) & 1u) v.w = 0.95f;
        }
        sin4[r][j] = v;
    }
    __syncthreads();

    // ---- phase B: vertical filter in registers, then horizontal + clip ----
    for (int i = tid; i < TH * 32; i += 256) {
        int rr = i >> 5;                       // output row within tile
        int j = i & 31;                        // output float4 word
        // Output word j = halo word j+1. Need v-filtered halo scalars
        // 4j+2 .. 4j+9: word j (.z,.w), word j+1 (all), word j+2 (.x,.y).
        float2 va = make_float2(0.f, 0.f);
        float4 vb = make_float4(0.f, 0.f, 0.f, 0.f);
        float2 vc = make_float2(0.f, 0.f);
        #pragma unroll
        for (int k = 0; k < 5; ++k) {
            const float wk = (k == 0 || k == 4) ? G0 : ((k == 1 || k == 3) ? G1 : G2);
            const float* row = (const float*)&sin4[rr + k][j];
            float2 a  = *(const float2*)(row + 2);   // word j   .z,.w
            float4 bv = *(const float4*)(row + 4);   // word j+1
            float2 cv = *(const float2*)(row + 8);   // word j+2 .x,.y
            va.x += wk * a.x;  va.y += wk * a.y;
            vb.x += wk * bv.x; vb.y += wk * bv.y;
            vb.z += wk * bv.z; vb.w += wk * bv.w;
            vc.x += wk * cv.x; vc.y += wk * cv.y;
        }
        float4 o;
        o.x = G0 * (va.x + vb.z) + G1 * (va.y + vb.y) + G2 * vb.x;
        o.y = G0 * (va.y + vb.w) + G1 * (vb.x + vb.z) + G2 * vb.y;
        o.z = G0 * (vb.x + vc.x) + G1 * (vb.y + vb.w) + G2 * vb.z;
        o.w = G0 * (vb.y + vc.y) + G1 * (vb.z + vc.x) + G2 * vb.w;
        o.x = fminf(fmaxf(o.x, 0.0f), 1.0f);
        o.y = fminf(fmaxf(o.y, 0.0f), 1.0f);
        o.z = fminf(fmaxf(o.z, 0.0f), 1.0f);
        o.w = fminf(fmaxf(o.w, 0.0f), 1.0f);
        *(float4*)(op + ((ty0 + rr) << 10) + tx0 + 4 * j) = o;
    }
}

extern "C" void kernel_launch(void* const* d_in, const int* in_sizes, int n_in,
                              void* d_out, int out_size, void* d_ws, size_t ws_size,
                              hipStream_t stream) {
    const float* x  = (const float*)d_in[0];
    const int*   ys = (const int*)d_in[1];
    const int*   xs = (const int*)d_in[2];
    const int*   rs = (const int*)d_in[3];
    float* out = (float*)d_out;
    unsigned int* mask = (unsigned int*)d_ws;  // 16 * 32768 words = 2 MB

    int n4 = B_ * MASK_WORDS_PER_B / 4;
    clear_mask_kernel<<<dim3((n4 + 255) / 256), dim3(256), 0, stream>>>((uint4*)mask, n4);

    int nst = B_ * NF_;
    stamp_kernel<<<dim3((nst + 255) / 256), dim3(256), 0, stream>>>(ys, xs, rs, mask);

    dim3 grid(W_ / TW, H_ / TH, B_ * C_);
    blur_kernel<<<grid, dim3(256), 0, stream>>>(x, mask, out);
}